// Round 15
// baseline (373.841 us; speedup 1.0000x reference)
//
#include <hip/hip_runtime.h>

typedef __bf16 bf16_t;
typedef bf16_t bf16x8 __attribute__((ext_vector_type(8)));
typedef float f32x4 __attribute__((ext_vector_type(4)));
typedef unsigned short u16;

#define MFMA16 __builtin_amdgcn_mfma_f32_16x16x32_bf16

#define NT_TOK   12288           // tokens per batch (L*N)
#define T_TOK    49152           // total tokens

// workspace layout (bytes), all 16B aligned (WS_PC/WS_S unused but kept
// so Wp/mTp/mFp offsets match k_init)
#define WS_PC    0               // (unused after fusion)
#define WS_S     25165824        // (unused after fusion)
#define WS_WP    29884416        // u16[32*10*64*8]    W frags, lane-packed (320 KB)
#define WS_MTP   30212096        // u16[24*16*64*8]    memT frags, lane-packed (384 KB)
#define WS_MFP   30605312        // u16[24*16*64*8]    memF frags, lane-packed (384 KB)
#define WS_SKL   30998528        // float[512]         per-(b,f) running max
#define WS_LOSS  31000576        // float[1]
#define WS_CTR   31000580        // unsigned[1]        k_fused completion counter

__device__ __forceinline__ u16 f2bf(float f) {
  union { bf16_t h; u16 u; } c; c.h = (bf16_t)f; return c.u;
}

__device__ __forceinline__ void atomic_max_f32(float* a, float v) {
  if (v >= 0.f) atomicMax((int*)a, __float_as_int(v));
  else atomicMin((unsigned int*)a, (unsigned int)__float_as_int(v));
}

// async global->LDS, 16B per lane, wave-uniform LDS base
#define GLD16(g, l) __builtin_amdgcn_global_load_lds( \
    (const __attribute__((address_space(1))) void*)(g), \
    (__attribute__((address_space(3))) void*)(l), 16, 0, 0)

// ---- init: pack W / memT / memF into fragment-major lane order ------------
__global__ void k_init(const float* __restrict__ seg_w, const float* __restrict__ pc_w,
                       const float* __restrict__ mem,
                       u16* __restrict__ Wp, u16* __restrict__ mTp, u16* __restrict__ mFp,
                       float* __restrict__ skl, float* __restrict__ loss,
                       unsigned* __restrict__ ctr)
{
  int i = blockIdx.x * 256 + threadIdx.x;
  union { u16 s[8]; uint4 v; } u;
  if (i < 20480) {                       // W: unit = (kc*10 + t)*64 + lane
    int lane = i & 63, blk = i >> 6;
    int kc = blk / 10, t = blk - kc * 10;
    int n = lane & 15, q = lane >> 4;
    int row = t * 16 + n;
    int k0 = kc * 32 + q * 8;
    #pragma unroll
    for (int e = 0; e < 8; ++e) {
      float v = 0.f;
      if (row < 24) v = seg_w[row * 1024 + k0 + e];
      else if (row < 152) v = pc_w[(row - 24) * 1024 + k0 + e];
      u.s[e] = f2bf(v);
    }
    *(uint4*)(Wp + (size_t)i * 8) = u.v;
  } else if ((i -= 20480) < 24576) {     // memT: unit = (j*16 + wv*4 + ks)*64 + lane
    int lane = i & 63, blk = i >> 6;
    int j = blk >> 4, rem = blk & 15, wv = rem >> 2, ks = rem & 3;
    int n = lane & 15, q = lane >> 4;
    int slot = j * 64 + wv * 16 + n;
    int d0 = ks * 32 + q * 8;
    #pragma unroll
    for (int e = 0; e < 8; ++e)
      u.s[e] = f2bf(mem[(size_t)(d0 + e) * 1536 + slot]);
    *(uint4*)(mTp + (size_t)i * 8) = u.v;
  } else if ((i -= 24576) < 24576) {     // memF: unit = (j*16 + h*8 + wv*2 + ft)*64 + lane
    int lane = i & 63, blk = i >> 6;
    int j = blk >> 4, h = (blk >> 3) & 1, wv = (blk >> 1) & 3, ft = blk & 1;
    int n = lane & 15, q = lane >> 4;
    int f = wv * 32 + ft * 16 + n;
    int s0 = j * 64 + h * 32 + q * 8;
    #pragma unroll
    for (int e = 0; e < 8; ++e)
      u.s[e] = f2bf(mem[(size_t)f * 1536 + s0 + e]);
    *(uint4*)(mFp + (size_t)i * 8) = u.v;
  } else if ((i -= 24576) < 512) {
    skl[i] = -__builtin_inff();
  } else if (i == 512) {
    *loss = 0.f;
  } else if (i == 513) {
    *ctr = 0u;
  }
}

// ================= fused projection + attention + head =====================
// r14 proven body (355-356us) with ONE launch-structure change: the separate
// k_head dispatch is folded in via the standard last-block pattern --
// after each block's skl/loss atomics, tid0 does threadfence + atomicAdd on
// a completion counter; the block observing old==767 runs the head. No
// dispatch-order assumption (whichever block is last runs the tail ->
// deadlock-free). skl/loss are only ever written by device-scope atomics;
// the tail reads them with atomicAdd(p, 0.f) (coherent read, immune to
// per-XCD L2 staleness). Counter re-zeroed by k_init each iteration.
// Phase A = K-rotation, counted vmcnt 8/4/0, depth-3 feat regs, 40 KB W
// double-buffer via global_load_lds, setprio around MFMA.
// Phase B = per-j loop: Pl double-buffer, single lgkm-drain barrier per j,
// Pl XOR-swizzle, deep bm/sj rotation, j<23-guarded rotations (UB lesson).
#define FS_PCL   0               // u16[64][136]  = 17408   (overlays wbuf)
#define FS_PL    17408           // u16[2][64][80] = 20480
#define FS_LW    37888           // float[4][64]  = 1024
#define FS_RL    38912           // float[4]      = 16 (reused as last-flag)
#define FS_ST    40960           // float[64][26] = 6656 (reused by head)
#define FS_TOT   47616

__global__ __launch_bounds__(256, 3) void k_fused(
    const float* __restrict__ feat, const u16* __restrict__ Wp,
    const float* __restrict__ seg_b, const float* __restrict__ pc_b,
    const u16* __restrict__ mFp, const u16* __restrict__ mTp,
    float* __restrict__ outp, float* __restrict__ skl, float* __restrict__ loss,
    unsigned* __restrict__ ctr,
    const float* __restrict__ ln_g, const float* __restrict__ ln_b,
    const float* __restrict__ w1, const float* __restrict__ b1,
    const float* __restrict__ w2, const float* __restrict__ b2)
{
  __shared__ __align__(16) char smem[FS_TOT];
  u16*    wb     = (u16*)smem;                   // [2][10240] (phase A)
  bf16_t* pcl    = (bf16_t*)(smem + FS_PCL);     // [64][136] bf16 (phase B)
  u16*    Pl     = (u16*)(smem + FS_PL);         // [2][64][80]
  float*  lw     = (float*)(smem + FS_LW);
  float*  redL   = (float*)(smem + FS_RL);
  float*  s_tile = (float*)(smem + FS_ST);

  float* out_seg = outp + 288;

  const int tid = threadIdx.x;
  const int w = tid >> 6;
  const int lane = tid & 63;
  const int n = lane & 15;
  const int q = lane >> 4;
  const int base = blockIdx.x * 64;
  const int c0 = (blockIdx.x % 3) * 5;          // K-rotation phase offset
  const int swz = (n & 12) << 1;                // Pl bank swizzle (u16 units)

  // ======================= phase A: projection =======================
  f32x4 acc[10];
  #pragma unroll
  for (int t = 0; t < 10; ++t) acc[t] = (f32x4){0.f, 0.f, 0.f, 0.f};

  const float* fp0 = feat + (size_t)(base + w * 16 + n) * 1024 + q * 8;

  // ---- prologue: stage chunk c0 (W), load feat chunks c0, c0+1
  {
    const u16* gW = Wp + (size_t)c0 * 10240;
    #pragma unroll
    for (int i = 0; i < 5; ++i) {
      const int off = i * 2048 + w * 512;
      GLD16(gW + off + lane * 8, wb + off);
    }
  }
  __builtin_amdgcn_sched_barrier(0);
  float4 fb[3][2][2];                           // [lc%3][kc2][half], static idx only
  #pragma unroll
  for (int cc = 0; cc < 2; ++cc)
    #pragma unroll
    for (int kc2 = 0; kc2 < 2; ++kc2) {
      const float4* a = (const float4*)(fp0 + (((c0 + cc) & 15) * 2 + kc2) * 32);
      fb[cc][kc2][0] = a[0];
      fb[cc][kc2][1] = a[1];
    }
  // outstanding: GLD(c0) x5 (oldest) + feat x8 = 13 -> vmcnt(8): chunk staged
  asm volatile("s_waitcnt vmcnt(8)" ::: "memory");
  __builtin_amdgcn_s_barrier();
  __builtin_amdgcn_sched_barrier(0);

  #pragma unroll
  for (int lc = 0; lc < 16; ++lc) {             // loop counter; chunk = (c0+lc)&15
    if (lc < 15) {
      const u16* gW = Wp + (size_t)((c0 + lc + 1) & 15) * 10240;
      u16* nb = wb + ((lc + 1) & 1) * 10240;
      #pragma unroll
      for (int i = 0; i < 5; ++i) {
        const int off = i * 2048 + w * 512;
        GLD16(gW + off + lane * 8, nb + off);
      }
      __builtin_amdgcn_sched_barrier(0);   // pin: feat loads stay below GLDs
    }
    if (lc < 14) {
      #pragma unroll
      for (int kc2 = 0; kc2 < 2; ++kc2) {
        const float4* a = (const float4*)(fp0 + (((c0 + lc + 2) & 15) * 2 + kc2) * 32);
        fb[(lc + 2) % 3][kc2][0] = a[0];
        fb[(lc + 2) % 3][kc2][1] = a[1];
      }
    }

    const u16* lb = wb + (lc & 1) * 10240;
    #pragma unroll
    for (int kc2 = 0; kc2 < 2; ++kc2) {
      bf16x8 bw[10];
      #pragma unroll
      for (int t = 0; t < 10; ++t)
        bw[t] = *(const bf16x8*)(lb + (size_t)(kc2 * 10 + t) * 512 + lane * 8);
      float4 x0 = fb[lc % 3][kc2][0], y0 = fb[lc % 3][kc2][1];
      bf16x8 af;
      af[0] = (bf16_t)x0.x; af[1] = (bf16_t)x0.y; af[2] = (bf16_t)x0.z; af[3] = (bf16_t)x0.w;
      af[4] = (bf16_t)y0.x; af[5] = (bf16_t)y0.y; af[6] = (bf16_t)y0.z; af[7] = (bf16_t)y0.w;
      __builtin_amdgcn_s_setprio(1);
      #pragma unroll
      for (int t = 0; t < 10; ++t)
        acc[t] = MFMA16(af, bw[t], acc[t], 0, 0, 0);
      __builtin_amdgcn_s_setprio(0);
    }

    if (lc < 15) {
      if (lc < 14) asm volatile("s_waitcnt vmcnt(4)" ::: "memory");
      else         asm volatile("s_waitcnt vmcnt(0)" ::: "memory");
      __builtin_amdgcn_s_barrier();
      __builtin_amdgcn_sched_barrier(0);
    }
  }

  // ---- transition 1: all waves done reading wbuf before it is overlaid
  asm volatile("s_waitcnt lgkmcnt(0)" ::: "memory");
  __builtin_amdgcn_sched_barrier(0);
  __builtin_amdgcn_s_barrier();
  __builtin_amdgcn_sched_barrier(0);

  // ---- epilogue: seg softmax -> s_tile + out_seg ; biased pc -> pcl (bf16)
  #pragma unroll
  for (int r = 0; r < 4; ++r) {
    const int tl = w * 16 + q * 4 + r;          // block-local token
    const int token = base + tl;
    float v0 = acc[0][r] + seg_b[n];
    float v1 = (n < 8) ? (acc[1][r] + seg_b[16 + n]) : -__builtin_inff();
    float mx = fmaxf(v0, v1);
    #pragma unroll
    for (int d2 = 1; d2 < 16; d2 <<= 1) mx = fmaxf(mx, __shfl_xor(mx, d2, 16));
    float e0 = __expf(v0 - mx);
    float e1 = (n < 8) ? __expf(v1 - mx) : 0.f;
    float sm = e0 + e1;
    #pragma unroll
    for (int d2 = 1; d2 < 16; d2 <<= 1) sm += __shfl_xor(sm, d2, 16);
    float is = 1.f / sm;
    float s0v = e0 * is, s1v = e1 * is;
    s_tile[tl * 26 + n] = s0v;
    if (n < 8) s_tile[tl * 26 + 16 + n] = s1v;
    const int b = token / NT_TOK;
    const int rem = token - b * NT_TOK;
    const int l = rem >> 9, p = rem & 511;
    float* so = out_seg + ((size_t)(b * 24 + l) * 24) * 512 + p;
    so[(size_t)n * 512] = s0v;
    if (n < 8) so[(size_t)(16 + n) * 512] = s1v;
    #pragma unroll
    for (int t = 1; t < 10; ++t) {
      int col = t * 16 + n;
      if (col >= 24 && col < 152) {
        pcl[tl * 136 + (col - 24)] = (bf16_t)(acc[t][r] + pc_b[col - 24]);
      }
    }
  }

  // ---- transition 2: pcl / s_tile visible to all waves
  asm volatile("s_waitcnt lgkmcnt(0)" ::: "memory");
  __builtin_amdgcn_sched_barrier(0);
  __builtin_amdgcn_s_barrier();
  __builtin_amdgcn_sched_barrier(0);

  // ======================= phase B: attention =======================
  const u16* mT_frag = mTp + (size_t)(w * 4) * 512 + lane * 8;   // + (j*16 + ks)*512
  const u16* mF_frag = mFp + (size_t)(w * 2) * 512 + lane * 8;   // + (j*16 + h*8 + ft)*512

  // preload j=0 operands: QK A-ops, PV B-ops (global), s_tile scales (LDS)
  bf16x8 amc[4], bmc[4];
  #pragma unroll
  for (int ks = 0; ks < 4; ++ks)
    amc[ks] = *(const bf16x8*)(mT_frag + (size_t)ks * 512);
  #pragma unroll
  for (int hf = 0; hf < 4; ++hf)
    bmc[hf] = *(const bf16x8*)(mF_frag + (size_t)((hf >> 1) * 8 + (hf & 1)) * 512);

  // Q fragments (B-operand layout) straight from the bf16 pc tile (no cvt)
  bf16x8 qf[4][4];                     // [tok-tile][ks]
  #pragma unroll
  for (int tt = 0; tt < 4; ++tt)
    #pragma unroll
    for (int ks = 0; ks < 4; ++ks)
      qf[tt][ks] = *(const bf16x8*)(pcl + (size_t)(tt * 16 + n) * 136 + ks * 32 + q * 8);

  const float invs = 0.088388347648318447f; // 1/sqrt(128)
  float sjc[4], sjn[4];
  #pragma unroll
  for (int tt = 0; tt < 4; ++tt)
    sjc[tt] = s_tile[(tt * 16 + n) * 26 + 0] * invs;

  f32x4 o[4][2];                       // [tok-tile][f-tile], f = w*32 + ft*16 + n
  #pragma unroll
  for (int tt = 0; tt < 4; ++tt) {
    o[tt][0] = (f32x4){0.f, 0.f, 0.f, 0.f};
    o[tt][1] = (f32x4){0.f, 0.f, 0.f, 0.f};
  }
  float l_acc[4] = {0.f, 0.f, 0.f, 0.f};

  for (int j = 0; j < 24; ++j) {
    u16* Plj = Pl + (j & 1) * 5120;         // this j's P buffer (u16 elems)

    // S^T tile: this wave owns slots [w*16, w*16+16) x 64 tokens
    f32x4 sacc[4];
    #pragma unroll
    for (int tt = 0; tt < 4; ++tt) sacc[tt] = (f32x4){0.f, 0.f, 0.f, 0.f};
    __builtin_amdgcn_s_setprio(1);
    #pragma unroll
    for (int ks = 0; ks < 4; ++ks) {
      #pragma unroll
      for (int tt = 0; tt < 4; ++tt)
        sacc[tt] = MFMA16(amc[ks], qf[tt][ks], sacc[tt], 0, 0, 0);
    }
    __builtin_amdgcn_s_setprio(0);

    // prefetch next j's QK A-operands (consumed at the top of iter j+1)
    bf16x8 amn[4];
    if (j < 23) {
      #pragma unroll
      for (int ks = 0; ks < 4; ++ks)
        amn[ks] = *(const bf16x8*)(mT_frag + (size_t)((j + 1) * 16 + ks) * 512);
    }

    // exp + pack P into Pl[j&1], swizzled columns (scales sjc in registers)
    #pragma unroll
    for (int tt = 0; tt < 4; ++tt) {
      float p0 = __expf(sacc[tt][0] * sjc[tt]);
      float p1 = __expf(sacc[tt][1] * sjc[tt]);
      float p2 = __expf(sacc[tt][2] * sjc[tt]);
      float p3 = __expf(sacc[tt][3] * sjc[tt]);
      l_acc[tt] += (p0 + p1) + (p2 + p3);
      ushort4 pk;
      pk.x = f2bf(p0); pk.y = f2bf(p1); pk.z = f2bf(p2); pk.w = f2bf(p3);
      *(ushort4*)(&Plj[(tt * 16 + n) * 80 + ((w * 16 + q * 4) ^ swz)]) = pk;
    }

    // ---- single barrier per j: Pl[j&1] writes visible. LDS drain only --
    // in-flight global prefetches (amn, bm) ride across.
    asm volatile("s_waitcnt lgkmcnt(0)" ::: "memory");
    __builtin_amdgcn_sched_barrier(0);
    __builtin_amdgcn_s_barrier();
    __builtin_amdgcn_sched_barrier(0);

    // deep prefetch for j+1: PV B-ops (consumed after barrier(j+1), ~700 cy)
    // and s_tile scales (consumed in exp(j+1))
    bf16x8 bmn[4];
    if (j < 23) {
      #pragma unroll
      for (int hf = 0; hf < 4; ++hf)
        bmn[hf] = *(const bf16x8*)(mF_frag + (size_t)((j + 1) * 16 + (hf >> 1) * 8 + (hf & 1)) * 512);
      #pragma unroll
      for (int tt = 0; tt < 4; ++tt)
        sjn[tt] = s_tile[(tt * 16 + n) * 26 + (j + 1)] * invs;
    }

    // PV: this wave owns f in [w*32, w*32+32) x 64 tokens. Reads use the
    // same per-row XOR as the writes: Plj[row][c ^ swz(row)] holds slot c.
    __builtin_amdgcn_s_setprio(1);
    #pragma unroll
    for (int tt = 0; tt < 4; ++tt) {
      bf16x8 pa0 = *(const bf16x8*)(&Plj[(tt * 16 + n) * 80 + ((q * 8) ^ swz)]);
      o[tt][0] = MFMA16(pa0, bmc[0], o[tt][0], 0, 0, 0);
      o[tt][1] = MFMA16(pa0, bmc[1], o[tt][1], 0, 0, 0);
      bf16x8 pa1 = *(const bf16x8*)(&Plj[(tt * 16 + n) * 80 + 32 + ((q * 8) ^ swz)]);
      o[tt][0] = MFMA16(pa1, bmc[2], o[tt][0], 0, 0, 0);
      o[tt][1] = MFMA16(pa1, bmc[3], o[tt][1], 0, 0, 0);
    }
    __builtin_amdgcn_s_setprio(0);

    // rotation copies GUARDED (j==23 must not read uninitialized amn/bmn/sjn)
    if (j < 23) {
      #pragma unroll
      for (int ks = 0; ks < 4; ++ks) amc[ks] = amn[ks];
      #pragma unroll
      for (int hf = 0; hf < 4; ++hf) bmc[hf] = bmn[hf];
      #pragma unroll
      for (int tt = 0; tt < 4; ++tt) sjc[tt] = sjn[tt];
    }
  }

  // l reduction: per-wave partials (sum over q) -> LDS -> sum over waves
  #pragma unroll
  for (int tt = 0; tt < 4; ++tt) {
    float v = l_acc[tt];
    v += __shfl_xor(v, 16, 64);
    v += __shfl_xor(v, 32, 64);
    if (q == 0) lw[w * 64 + tt * 16 + n] = v;
  }
  __syncthreads();

  // epilogue: rec = O/l, loss partial, per-f max (pc reference from bf16 LDS)
  float lsum = 0.f;
  float fmax2[2] = {-__builtin_inff(), -__builtin_inff()};
  #pragma unroll
  for (int tt = 0; tt < 4; ++tt) {
    f32x4 linv;
    #pragma unroll
    for (int r = 0; r < 4; ++r) {
      int tok = tt * 16 + q * 4 + r;
      float lt = lw[tok] + lw[64 + tok] + lw[128 + tok] + lw[192 + tok];
      linv[r] = 1.f / lt;
    }
    #pragma unroll
    for (int ft = 0; ft < 2; ++ft)
      #pragma unroll
      for (int r = 0; r < 4; ++r) {
        const int tl = tt * 16 + q * 4 + r;
        const int f = w * 32 + ft * 16 + n;
        float rec = o[tt][ft][r] * linv[r];
        float d = rec - (float)pcl[(size_t)tl * 136 + f];
        lsum += d * d;
        fmax2[ft] = fmaxf(fmax2[ft], rec);
      }
  }
  #pragma unroll
  for (int ft = 0; ft < 2; ++ft) {
    float v = fmax2[ft];
    v = fmaxf(v, __shfl_xor(v, 16, 64));
    v = fmaxf(v, __shfl_xor(v, 32, 64));
    if (q == 0) atomic_max_f32(&skl[(base / NT_TOK) * 128 + w * 32 + ft * 16 + n], v);
  }
  #pragma unroll
  for (int d2 = 1; d2 < 64; d2 <<= 1) lsum += __shfl_xor(lsum, d2, 64);
  if (lane == 0) redL[w] = lsum;
  __syncthreads();

  // ---- last-block tail: loss add -> fence -> counter; block 768 runs head.
  // The preceding __syncthreads drained every wave's vmcnt, so all skl
  // atomics of this block are complete before the counter increment.
  int* flg = (int*)redL;
  if (tid == 0) {
    atomicAdd(loss, redL[0] + redL[1] + redL[2] + redL[3]);
    __threadfence();
    unsigned old = atomicAdd(ctr, 1u);
    flg[0] = (old == 767u) ? 1 : 0;
  }
  __syncthreads();
  if (flg[0] == 0) return;

  // ======================= head (tail block only) =====================
  __threadfence();
  float* hb = (float*)(smem + FS_ST);   // 128 floats (s_tile area, now free)
  float* gb = hb + 128;                 // 64
  float* rd = gb + 64;                  // 4
  const int t = tid;
  float lossv = 0.f;
  if (t == 0) lossv = atomicAdd(loss, 0.f);          // coherent read
  for (int b = 0; b < 4; ++b) {
    float x = 0.f;
    if (t < 128) {
      x = atomicAdd(&skl[b * 128 + t], 0.f);         // coherent read
      float s1 = x, s2 = x * x;
      #pragma unroll
      for (int d = 1; d < 64; d <<= 1) {
        s1 += __shfl_xor(s1, d, 64);
        s2 += __shfl_xor(s2, d, 64);
      }
      if ((t & 63) == 0) { rd[(t >> 6) * 2] = s1; rd[(t >> 6) * 2 + 1] = s2; }
    }
    __syncthreads();
    if (t < 128) {
      float mu = (rd[0] + rd[2]) * (1.f / 128.f);
      float var = (rd[1] + rd[3]) * (1.f / 128.f) - mu * mu;
      hb[t] = (x - mu) * rsqrtf(var + 1e-5f) * ln_g[t] + ln_b[t];
    }
    __syncthreads();
    if (t < 64) {
      float a = b1[t];
      for (int c2 = 0; c2 < 128; ++c2) a += hb[c2] * w1[t * 128 + c2];
      gb[t] = 0.5f * a * (1.f + erff(a * 0.70710678118654752f));
    }
    __syncthreads();
    if (t < 72) {
      float a = b2[t];
      for (int c2 = 0; c2 < 64; ++c2) a += gb[c2] * w2[t * 64 + c2];
      outp[b * 72 + t] = a;
    }
    __syncthreads();
  }
  if (t == 0) outp[1179936] = lossv * (1.f / 6291456.f);
}

extern "C" void kernel_launch(void* const* d_in, const int* in_sizes, int n_in,
                              void* d_out, int out_size, void* d_ws, size_t ws_size,
                              hipStream_t stream) {
  (void)in_sizes; (void)n_in; (void)out_size; (void)ws_size;
  const float* feat  = (const float*)d_in[0];
  const float* seg_w = (const float*)d_in[1];
  const float* seg_b = (const float*)d_in[2];
  const float* pc_w  = (const float*)d_in[3];
  const float* pc_b  = (const float*)d_in[4];
  const float* mem   = (const float*)d_in[5];
  const float* ln_g  = (const float*)d_in[6];
  const float* ln_b  = (const float*)d_in[7];
  const float* w1    = (const float*)d_in[8];
  const float* b1    = (const float*)d_in[9];
  const float* w2    = (const float*)d_in[10];
  const float* b2    = (const float*)d_in[11];

  char* ws = (char*)d_ws;
  u16*      Wp   = (u16*)(ws + WS_WP);
  u16*      mTp  = (u16*)(ws + WS_MTP);
  u16*      mFp  = (u16*)(ws + WS_MFP);
  float*    sklb = (float*)(ws + WS_SKL);
  float*    lossb= (float*)(ws + WS_LOSS);
  unsigned* ctrb = (unsigned*)(ws + WS_CTR);
  float*    out  = (float*)d_out;

  k_init<<<275, 256, 0, stream>>>(seg_w, pc_w, mem, Wp, mTp, mFp, sklb, lossb, ctrb);
  k_fused<<<768, 256, 0, stream>>>(feat, Wp, seg_b, pc_b, mFp, mTp, out, sklb, lossb, ctrb,
                                   ln_g, ln_b, w1, b1, w2, b2);
}

// Round 16
// 354.936 us; speedup vs baseline: 1.0533x; 1.0533x over previous
//
#include <hip/hip_runtime.h>

typedef __bf16 bf16_t;
typedef bf16_t bf16x8 __attribute__((ext_vector_type(8)));
typedef float f32x4 __attribute__((ext_vector_type(4)));
typedef unsigned short u16;

#define MFMA16 __builtin_amdgcn_mfma_f32_16x16x32_bf16

#define NT_TOK   12288           // tokens per batch (L*N)
#define T_TOK    49152           // total tokens

// workspace layout (bytes), all 16B aligned (WS_PC/WS_S unused but kept
// so Wp/mTp/mFp offsets match k_init)
#define WS_PC    0               // (unused after fusion)
#define WS_S     25165824        // (unused after fusion)
#define WS_WP    29884416        // u16[32*10*64*8]    W frags, lane-packed (320 KB)
#define WS_MTP   30212096        // u16[24*16*64*8]    memT frags, lane-packed (384 KB)
#define WS_MFP   30605312        // u16[24*16*64*8]    memF frags, lane-packed (384 KB)
#define WS_SKL   30998528        // float[512]         per-(b,f) running max
#define WS_LOSS  31000576        // float[1]

__device__ __forceinline__ u16 f2bf(float f) {
  union { bf16_t h; u16 u; } c; c.h = (bf16_t)f; return c.u;
}

__device__ __forceinline__ void atomic_max_f32(float* a, float v) {
  if (v >= 0.f) atomicMax((int*)a, __float_as_int(v));
  else atomicMin((unsigned int*)a, (unsigned int)__float_as_int(v));
}

// async global->LDS, 16B per lane, wave-uniform LDS base
#define GLD16(g, l) __builtin_amdgcn_global_load_lds( \
    (const __attribute__((address_space(1))) void*)(g), \
    (__attribute__((address_space(3))) void*)(l), 16, 0, 0)

// ---- init: pack W / memT / memF into fragment-major lane order ------------
__global__ void k_init(const float* __restrict__ seg_w, const float* __restrict__ pc_w,
                       const float* __restrict__ mem,
                       u16* __restrict__ Wp, u16* __restrict__ mTp, u16* __restrict__ mFp,
                       float* __restrict__ skl, float* __restrict__ loss)
{
  int i = blockIdx.x * 256 + threadIdx.x;
  union { u16 s[8]; uint4 v; } u;
  if (i < 20480) {                       // W: unit = (kc*10 + t)*64 + lane
    int lane = i & 63, blk = i >> 6;
    int kc = blk / 10, t = blk - kc * 10;
    int n = lane & 15, q = lane >> 4;
    int row = t * 16 + n;
    int k0 = kc * 32 + q * 8;
    #pragma unroll
    for (int e = 0; e < 8; ++e) {
      float v = 0.f;
      if (row < 24) v = seg_w[row * 1024 + k0 + e];
      else if (row < 152) v = pc_w[(row - 24) * 1024 + k0 + e];
      u.s[e] = f2bf(v);
    }
    *(uint4*)(Wp + (size_t)i * 8) = u.v;
  } else if ((i -= 20480) < 24576) {     // memT: unit = (j*16 + wv*4 + ks)*64 + lane
    int lane = i & 63, blk = i >> 6;
    int j = blk >> 4, rem = blk & 15, wv = rem >> 2, ks = rem & 3;
    int n = lane & 15, q = lane >> 4;
    int slot = j * 64 + wv * 16 + n;
    int d0 = ks * 32 + q * 8;
    #pragma unroll
    for (int e = 0; e < 8; ++e)
      u.s[e] = f2bf(mem[(size_t)(d0 + e) * 1536 + slot]);
    *(uint4*)(mTp + (size_t)i * 8) = u.v;
  } else if ((i -= 24576) < 24576) {     // memF: unit = (j*16 + h*8 + wv*2 + ft)*64 + lane
    int lane = i & 63, blk = i >> 6;
    int j = blk >> 4, h = (blk >> 3) & 1, wv = (blk >> 1) & 3, ft = blk & 1;
    int n = lane & 15, q = lane >> 4;
    int f = wv * 32 + ft * 16 + n;
    int s0 = j * 64 + h * 32 + q * 8;
    #pragma unroll
    for (int e = 0; e < 8; ++e)
      u.s[e] = f2bf(mem[(size_t)f * 1536 + s0 + e]);
    *(uint4*)(mFp + (size_t)i * 8) = u.v;
  } else if ((i -= 24576) < 512) {
    skl[i] = -__builtin_inff();
  } else if (i == 512) {
    *loss = 0.f;
  }
}

// ================= fused projection + attention ============================
// FINAL PROVEN STATE (r12: 355.2us, r14 repro: 356.1us). r15's head-fold
// regressed the main body's codegen (k_fused 133->167us, uniform) and was
// reverted. Session ledger: LDS W-staging + counted vmcnt (r2), fusion (r6),
// Pl stride fix (r8), Pl XOR-swizzle + 4-block k_head (r12) are the
// cumulative wins; K-rotation / setprio / deep-prefetch / j-pair /
// occupancy-4 / 32-tok / head-fold all null or negative (measured).
// Phase A = K-rotation, counted vmcnt 8/4/0, depth-3 feat regs, 40 KB W
// double-buffer via global_load_lds, setprio around MFMA.
// Phase B = per-j loop: Pl double-buffer (write j into Pl[j&1] while PV(j-1)
// reads the other), single lgkm-drain barrier per j, Pl XOR-swizzle
// (conflicts 3.76M->1.40M), deep bm/sj rotation, j<23-guarded rotations.
#define FS_PCL   0               // u16[64][136]  = 17408   (overlays wbuf)
#define FS_PL    17408           // u16[2][64][80] = 20480
#define FS_LW    37888           // float[4][64]  = 1024
#define FS_RL    38912           // float[4]      = 16
#define FS_ST    40960           // float[64][26] = 6656 (outside W region)
#define FS_TOT   47616

__global__ __launch_bounds__(256, 3) void k_fused(
    const float* __restrict__ feat, const u16* __restrict__ Wp,
    const float* __restrict__ seg_b, const float* __restrict__ pc_b,
    const u16* __restrict__ mFp, const u16* __restrict__ mTp,
    float* __restrict__ out_seg, float* __restrict__ skl, float* __restrict__ loss)
{
  __shared__ __align__(16) char smem[FS_TOT];
  u16*    wb     = (u16*)smem;                   // [2][10240] (phase A)
  bf16_t* pcl    = (bf16_t*)(smem + FS_PCL);     // [64][136] bf16 (phase B)
  u16*    Pl     = (u16*)(smem + FS_PL);         // [2][64][80]
  float*  lw     = (float*)(smem + FS_LW);
  float*  redL   = (float*)(smem + FS_RL);
  float*  s_tile = (float*)(smem + FS_ST);

  const int tid = threadIdx.x;
  const int w = tid >> 6;
  const int lane = tid & 63;
  const int n = lane & 15;
  const int q = lane >> 4;
  const int base = blockIdx.x * 64;
  const int c0 = (blockIdx.x % 3) * 5;          // K-rotation phase offset
  const int swz = (n & 12) << 1;                // Pl bank swizzle (u16 units)

  // ======================= phase A: projection =======================
  f32x4 acc[10];
  #pragma unroll
  for (int t = 0; t < 10; ++t) acc[t] = (f32x4){0.f, 0.f, 0.f, 0.f};

  const float* fp0 = feat + (size_t)(base + w * 16 + n) * 1024 + q * 8;

  // ---- prologue: stage chunk c0 (W), load feat chunks c0, c0+1
  {
    const u16* gW = Wp + (size_t)c0 * 10240;
    #pragma unroll
    for (int i = 0; i < 5; ++i) {
      const int off = i * 2048 + w * 512;
      GLD16(gW + off + lane * 8, wb + off);
    }
  }
  __builtin_amdgcn_sched_barrier(0);
  float4 fb[3][2][2];                           // [lc%3][kc2][half], static idx only
  #pragma unroll
  for (int cc = 0; cc < 2; ++cc)
    #pragma unroll
    for (int kc2 = 0; kc2 < 2; ++kc2) {
      const float4* a = (const float4*)(fp0 + (((c0 + cc) & 15) * 2 + kc2) * 32);
      fb[cc][kc2][0] = a[0];
      fb[cc][kc2][1] = a[1];
    }
  // outstanding: GLD(c0) x5 (oldest) + feat x8 = 13 -> vmcnt(8): chunk staged
  asm volatile("s_waitcnt vmcnt(8)" ::: "memory");
  __builtin_amdgcn_s_barrier();
  __builtin_amdgcn_sched_barrier(0);

  #pragma unroll
  for (int lc = 0; lc < 16; ++lc) {             // loop counter; chunk = (c0+lc)&15
    if (lc < 15) {
      const u16* gW = Wp + (size_t)((c0 + lc + 1) & 15) * 10240;
      u16* nb = wb + ((lc + 1) & 1) * 10240;
      #pragma unroll
      for (int i = 0; i < 5; ++i) {
        const int off = i * 2048 + w * 512;
        GLD16(gW + off + lane * 8, nb + off);
      }
      __builtin_amdgcn_sched_barrier(0);   // pin: feat loads stay below GLDs
    }
    if (lc < 14) {
      #pragma unroll
      for (int kc2 = 0; kc2 < 2; ++kc2) {
        const float4* a = (const float4*)(fp0 + (((c0 + lc + 2) & 15) * 2 + kc2) * 32);
        fb[(lc + 2) % 3][kc2][0] = a[0];
        fb[(lc + 2) % 3][kc2][1] = a[1];
      }
    }

    const u16* lb = wb + (lc & 1) * 10240;
    #pragma unroll
    for (int kc2 = 0; kc2 < 2; ++kc2) {
      bf16x8 bw[10];
      #pragma unroll
      for (int t = 0; t < 10; ++t)
        bw[t] = *(const bf16x8*)(lb + (size_t)(kc2 * 10 + t) * 512 + lane * 8);
      float4 x0 = fb[lc % 3][kc2][0], y0 = fb[lc % 3][kc2][1];
      bf16x8 af;
      af[0] = (bf16_t)x0.x; af[1] = (bf16_t)x0.y; af[2] = (bf16_t)x0.z; af[3] = (bf16_t)x0.w;
      af[4] = (bf16_t)y0.x; af[5] = (bf16_t)y0.y; af[6] = (bf16_t)y0.z; af[7] = (bf16_t)y0.w;
      __builtin_amdgcn_s_setprio(1);
      #pragma unroll
      for (int t = 0; t < 10; ++t)
        acc[t] = MFMA16(af, bw[t], acc[t], 0, 0, 0);
      __builtin_amdgcn_s_setprio(0);
    }

    if (lc < 15) {
      if (lc < 14) asm volatile("s_waitcnt vmcnt(4)" ::: "memory");
      else         asm volatile("s_waitcnt vmcnt(0)" ::: "memory");
      __builtin_amdgcn_s_barrier();
      __builtin_amdgcn_sched_barrier(0);
    }
  }

  // ---- transition 1: all waves done reading wbuf before it is overlaid
  asm volatile("s_waitcnt lgkmcnt(0)" ::: "memory");
  __builtin_amdgcn_sched_barrier(0);
  __builtin_amdgcn_s_barrier();
  __builtin_amdgcn_sched_barrier(0);

  // ---- epilogue: seg softmax -> s_tile + out_seg ; biased pc -> pcl (bf16)
  #pragma unroll
  for (int r = 0; r < 4; ++r) {
    const int tl = w * 16 + q * 4 + r;          // block-local token
    const int token = base + tl;
    float v0 = acc[0][r] + seg_b[n];
    float v1 = (n < 8) ? (acc[1][r] + seg_b[16 + n]) : -__builtin_inff();
    float mx = fmaxf(v0, v1);
    #pragma unroll
    for (int d2 = 1; d2 < 16; d2 <<= 1) mx = fmaxf(mx, __shfl_xor(mx, d2, 16));
    float e0 = __expf(v0 - mx);
    float e1 = (n < 8) ? __expf(v1 - mx) : 0.f;
    float sm = e0 + e1;
    #pragma unroll
    for (int d2 = 1; d2 < 16; d2 <<= 1) sm += __shfl_xor(sm, d2, 16);
    float is = 1.f / sm;
    float s0v = e0 * is, s1v = e1 * is;
    s_tile[tl * 26 + n] = s0v;
    if (n < 8) s_tile[tl * 26 + 16 + n] = s1v;
    const int b = token / NT_TOK;
    const int rem = token - b * NT_TOK;
    const int l = rem >> 9, p = rem & 511;
    float* so = out_seg + ((size_t)(b * 24 + l) * 24) * 512 + p;
    so[(size_t)n * 512] = s0v;
    if (n < 8) so[(size_t)(16 + n) * 512] = s1v;
    #pragma unroll
    for (int t = 1; t < 10; ++t) {
      int col = t * 16 + n;
      if (col >= 24 && col < 152) {
        pcl[tl * 136 + (col - 24)] = (bf16_t)(acc[t][r] + pc_b[col - 24]);
      }
    }
  }

  // ---- transition 2: pcl / s_tile visible to all waves
  asm volatile("s_waitcnt lgkmcnt(0)" ::: "memory");
  __builtin_amdgcn_sched_barrier(0);
  __builtin_amdgcn_s_barrier();
  __builtin_amdgcn_sched_barrier(0);

  // ======================= phase B: attention =======================
  const u16* mT_frag = mTp + (size_t)(w * 4) * 512 + lane * 8;   // + (j*16 + ks)*512
  const u16* mF_frag = mFp + (size_t)(w * 2) * 512 + lane * 8;   // + (j*16 + h*8 + ft)*512

  // preload j=0 operands: QK A-ops, PV B-ops (global), s_tile scales (LDS)
  bf16x8 amc[4], bmc[4];
  #pragma unroll
  for (int ks = 0; ks < 4; ++ks)
    amc[ks] = *(const bf16x8*)(mT_frag + (size_t)ks * 512);
  #pragma unroll
  for (int hf = 0; hf < 4; ++hf)
    bmc[hf] = *(const bf16x8*)(mF_frag + (size_t)((hf >> 1) * 8 + (hf & 1)) * 512);

  // Q fragments (B-operand layout) straight from the bf16 pc tile (no cvt)
  bf16x8 qf[4][4];                     // [tok-tile][ks]
  #pragma unroll
  for (int tt = 0; tt < 4; ++tt)
    #pragma unroll
    for (int ks = 0; ks < 4; ++ks)
      qf[tt][ks] = *(const bf16x8*)(pcl + (size_t)(tt * 16 + n) * 136 + ks * 32 + q * 8);

  const float invs = 0.088388347648318447f; // 1/sqrt(128)
  float sjc[4], sjn[4];
  #pragma unroll
  for (int tt = 0; tt < 4; ++tt)
    sjc[tt] = s_tile[(tt * 16 + n) * 26 + 0] * invs;

  f32x4 o[4][2];                       // [tok-tile][f-tile], f = w*32 + ft*16 + n
  #pragma unroll
  for (int tt = 0; tt < 4; ++tt) {
    o[tt][0] = (f32x4){0.f, 0.f, 0.f, 0.f};
    o[tt][1] = (f32x4){0.f, 0.f, 0.f, 0.f};
  }
  float l_acc[4] = {0.f, 0.f, 0.f, 0.f};

  for (int j = 0; j < 24; ++j) {
    u16* Plj = Pl + (j & 1) * 5120;         // this j's P buffer (u16 elems)

    // S^T tile: this wave owns slots [w*16, w*16+16) x 64 tokens
    f32x4 sacc[4];
    #pragma unroll
    for (int tt = 0; tt < 4; ++tt) sacc[tt] = (f32x4){0.f, 0.f, 0.f, 0.f};
    __builtin_amdgcn_s_setprio(1);
    #pragma unroll
    for (int ks = 0; ks < 4; ++ks) {
      #pragma unroll
      for (int tt = 0; tt < 4; ++tt)
        sacc[tt] = MFMA16(amc[ks], qf[tt][ks], sacc[tt], 0, 0, 0);
    }
    __builtin_amdgcn_s_setprio(0);

    // prefetch next j's QK A-operands (consumed at the top of iter j+1)
    bf16x8 amn[4];
    if (j < 23) {
      #pragma unroll
      for (int ks = 0; ks < 4; ++ks)
        amn[ks] = *(const bf16x8*)(mT_frag + (size_t)((j + 1) * 16 + ks) * 512);
    }

    // exp + pack P into Pl[j&1], swizzled columns (scales sjc in registers)
    #pragma unroll
    for (int tt = 0; tt < 4; ++tt) {
      float p0 = __expf(sacc[tt][0] * sjc[tt]);
      float p1 = __expf(sacc[tt][1] * sjc[tt]);
      float p2 = __expf(sacc[tt][2] * sjc[tt]);
      float p3 = __expf(sacc[tt][3] * sjc[tt]);
      l_acc[tt] += (p0 + p1) + (p2 + p3);
      ushort4 pk;
      pk.x = f2bf(p0); pk.y = f2bf(p1); pk.z = f2bf(p2); pk.w = f2bf(p3);
      *(ushort4*)(&Plj[(tt * 16 + n) * 80 + ((w * 16 + q * 4) ^ swz)]) = pk;
    }

    // ---- single barrier per j: Pl[j&1] writes visible. LDS drain only --
    // in-flight global prefetches (amn, bm) ride across.
    asm volatile("s_waitcnt lgkmcnt(0)" ::: "memory");
    __builtin_amdgcn_sched_barrier(0);
    __builtin_amdgcn_s_barrier();
    __builtin_amdgcn_sched_barrier(0);

    // deep prefetch for j+1: PV B-ops (consumed after barrier(j+1), ~700 cy)
    // and s_tile scales (consumed in exp(j+1))
    bf16x8 bmn[4];
    if (j < 23) {
      #pragma unroll
      for (int hf = 0; hf < 4; ++hf)
        bmn[hf] = *(const bf16x8*)(mF_frag + (size_t)((j + 1) * 16 + (hf >> 1) * 8 + (hf & 1)) * 512);
      #pragma unroll
      for (int tt = 0; tt < 4; ++tt)
        sjn[tt] = s_tile[(tt * 16 + n) * 26 + (j + 1)] * invs;
    }

    // PV: this wave owns f in [w*32, w*32+32) x 64 tokens. Reads use the
    // same per-row XOR as the writes: Plj[row][c ^ swz(row)] holds slot c.
    __builtin_amdgcn_s_setprio(1);
    #pragma unroll
    for (int tt = 0; tt < 4; ++tt) {
      bf16x8 pa0 = *(const bf16x8*)(&Plj[(tt * 16 + n) * 80 + ((q * 8) ^ swz)]);
      o[tt][0] = MFMA16(pa0, bmc[0], o[tt][0], 0, 0, 0);
      o[tt][1] = MFMA16(pa0, bmc[1], o[tt][1], 0, 0, 0);
      bf16x8 pa1 = *(const bf16x8*)(&Plj[(tt * 16 + n) * 80 + 32 + ((q * 8) ^ swz)]);
      o[tt][0] = MFMA16(pa1, bmc[2], o[tt][0], 0, 0, 0);
      o[tt][1] = MFMA16(pa1, bmc[3], o[tt][1], 0, 0, 0);
    }
    __builtin_amdgcn_s_setprio(0);

    // rotation copies GUARDED (j==23 must not read uninitialized amn/bmn/sjn)
    if (j < 23) {
      #pragma unroll
      for (int ks = 0; ks < 4; ++ks) amc[ks] = amn[ks];
      #pragma unroll
      for (int hf = 0; hf < 4; ++hf) bmc[hf] = bmn[hf];
      #pragma unroll
      for (int tt = 0; tt < 4; ++tt) sjc[tt] = sjn[tt];
    }
  }

  // l reduction: per-wave partials (sum over q) -> LDS -> sum over waves
  #pragma unroll
  for (int tt = 0; tt < 4; ++tt) {
    float v = l_acc[tt];
    v += __shfl_xor(v, 16, 64);
    v += __shfl_xor(v, 32, 64);
    if (q == 0) lw[w * 64 + tt * 16 + n] = v;
  }
  __syncthreads();

  // epilogue: rec = O/l, loss partial, per-f max (pc reference from bf16 LDS)
  float lsum = 0.f;
  float fmax2[2] = {-__builtin_inff(), -__builtin_inff()};
  #pragma unroll
  for (int tt = 0; tt < 4; ++tt) {
    f32x4 linv;
    #pragma unroll
    for (int r = 0; r < 4; ++r) {
      int tok = tt * 16 + q * 4 + r;
      float lt = lw[tok] + lw[64 + tok] + lw[128 + tok] + lw[192 + tok];
      linv[r] = 1.f / lt;
    }
    #pragma unroll
    for (int ft = 0; ft < 2; ++ft)
      #pragma unroll
      for (int r = 0; r < 4; ++r) {
        const int tl = tt * 16 + q * 4 + r;
        const int f = w * 32 + ft * 16 + n;
        float rec = o[tt][ft][r] * linv[r];
        float d = rec - (float)pcl[(size_t)tl * 136 + f];
        lsum += d * d;
        fmax2[ft] = fmaxf(fmax2[ft], rec);
      }
  }
  #pragma unroll
  for (int ft = 0; ft < 2; ++ft) {
    float v = fmax2[ft];
    v = fmaxf(v, __shfl_xor(v, 16, 64));
    v = fmaxf(v, __shfl_xor(v, 32, 64));
    if (q == 0) atomic_max_f32(&skl[(base / NT_TOK) * 128 + w * 32 + ft * 16 + n], v);
  }
  #pragma unroll
  for (int d2 = 1; d2 < 64; d2 <<= 1) lsum += __shfl_xor(lsum, d2, 64);
  if (lane == 0) redL[w] = lsum;
  __syncthreads();
  if (tid == 0) atomicAdd(loss, redL[0] + redL[1] + redL[2] + redL[3]);
}

// ---------------- head: LN -> Linear -> GELU -> Linear + loss finalize -----
// 4 blocks, one per batch b (batches independent). Block 0 writes the loss.
__global__ void k_head(const float* __restrict__ skl,
                       const float* __restrict__ ln_g, const float* __restrict__ ln_b,
                       const float* __restrict__ w1, const float* __restrict__ b1,
                       const float* __restrict__ w2, const float* __restrict__ b2,
                       const float* __restrict__ loss, float* __restrict__ out)
{
  __shared__ float hbuf[128];
  __shared__ float gbuf[64];
  __shared__ float red[4];
  const int t = threadIdx.x;            // 128 threads
  const int b = blockIdx.x;             // batch
  const int ln = t & 63, wv = t >> 6;
  float x = skl[b * 128 + t];
  float s1 = x, s2 = x * x;
  #pragma unroll
  for (int d = 1; d < 64; d <<= 1) {
    s1 += __shfl_xor(s1, d, 64);
    s2 += __shfl_xor(s2, d, 64);
  }
  if (ln == 0) { red[wv * 2] = s1; red[wv * 2 + 1] = s2; }
  __syncthreads();
  float mu = (red[0] + red[2]) * (1.f / 128.f);
  float var = (red[1] + red[3]) * (1.f / 128.f) - mu * mu;
  float hn = (x - mu) * rsqrtf(var + 1e-5f) * ln_g[t] + ln_b[t];
  hbuf[t] = hn;
  __syncthreads();
  if (t < 64) {
    float a = b1[t];
    for (int c = 0; c < 128; ++c) a += hbuf[c] * w1[t * 128 + c];
    gbuf[t] = 0.5f * a * (1.f + erff(a * 0.70710678118654752f));
  }
  __syncthreads();
  if (t < 72) {
    float a = b2[t];
    for (int c = 0; c < 64; ++c) a += gbuf[c] * w2[t * 64 + c];
    out[b * 72 + t] = a;
  }
  if (b == 0 && t == 0) out[1179936] = loss[0] * (1.f / 6291456.f);
}

extern "C" void kernel_launch(void* const* d_in, const int* in_sizes, int n_in,
                              void* d_out, int out_size, void* d_ws, size_t ws_size,
                              hipStream_t stream) {
  (void)in_sizes; (void)n_in; (void)out_size; (void)ws_size;
  const float* feat  = (const float*)d_in[0];
  const float* seg_w = (const float*)d_in[1];
  const float* seg_b = (const float*)d_in[2];
  const float* pc_w  = (const float*)d_in[3];
  const float* pc_b  = (const float*)d_in[4];
  const float* mem   = (const float*)d_in[5];
  const float* ln_g  = (const float*)d_in[6];
  const float* ln_b  = (const float*)d_in[7];
  const float* w1    = (const float*)d_in[8];
  const float* b1    = (const float*)d_in[9];
  const float* w2    = (const float*)d_in[10];
  const float* b2    = (const float*)d_in[11];

  char* ws = (char*)d_ws;
  u16*   Wp     = (u16*)(ws + WS_WP);
  u16*   mTp    = (u16*)(ws + WS_MTP);
  u16*   mFp    = (u16*)(ws + WS_MFP);
  float* sklb   = (float*)(ws + WS_SKL);
  float* lossb  = (float*)(ws + WS_LOSS);
  float* out    = (float*)d_out;

  k_init<<<275, 256, 0, stream>>>(seg_w, pc_w, mem, Wp, mTp, mFp, sklb, lossb);
  k_fused<<<768, 256, 0, stream>>>(feat, Wp, seg_b, pc_b, mFp, mTp, out + 288, sklb, lossb);
  k_head<<<4, 128, 0, stream>>>(sklb, ln_g, ln_b, w1, b1, w2, b2, lossb, out);
}